// Round 1
// baseline (353.878 us; speedup 1.0000x reference)
//
#include <hip/hip_runtime.h>
#include <hip/hip_fp8.h>
#include <stdint.h>

#define K_DIM 4096
#define N_DIM 4096
#define KB_CNT 32   // K / 128

using f32x4 = __attribute__((ext_vector_type(4))) float;

// async global->LDS, 16B per lane, linear dest (wave-uniform base + lane*16)
#define GLOAD_LDS16(g, l)                                                      \
    __builtin_amdgcn_global_load_lds(                                          \
        (const __attribute__((address_space(1))) unsigned int*)(g),            \
        (__attribute__((address_space(3))) unsigned int*)(l), 16, 0, 0)

__device__ __forceinline__ uint8_t to_fp8(float v) {
    __hip_fp8_e4m3 q(v);   // OCP e4m3fn, RNE saturating (gfx950 HW cvt)
    return (uint8_t)q.__x;
}

// ---------------- activation quant: one wave per (m, kb) ----------------
__global__ __launch_bounds__(256) void act_quant_kernel(
    const float* __restrict__ x, uint8_t* __restrict__ xq,
    float* __restrict__ sa)
{
    int gw   = blockIdx.x * 4 + (threadIdx.x >> 6);
    int lane = threadIdx.x & 63;
    int m    = gw >> 5;
    int kb   = gw & 31;
    size_t base = (size_t)m * K_DIM + kb * 128 + lane * 2;
    float2 v = *(const float2*)(x + base);
    float amax = fmaxf(fabsf(v.x), fabsf(v.y));
    #pragma unroll
    for (int o = 32; o >= 1; o >>= 1) amax = fmaxf(amax, __shfl_xor(amax, o));
    float s = amax / 448.0f;          // IEEE div, matches jnp exactly
    uchar2 q;
    q.x = to_fp8(v.x / s);            // IEEE div to match reference rounding
    q.y = to_fp8(v.y / s);
    *(uchar2*)(xq + base) = q;
    if (lane == 0) sa[(size_t)m * KB_CNT + kb] = s;
}

// ---------------- weight quant: f32 (exact fp8 values) -> bytes ----------------
__global__ __launch_bounds__(256) void w_quant_kernel(
    const float* __restrict__ w, uint8_t* __restrict__ wq)
{
    size_t i = ((size_t)blockIdx.x * 256 + threadIdx.x) * 4;
    float4 v = *(const float4*)(w + i);
    uchar4 q;
    q.x = to_fp8(v.x); q.y = to_fp8(v.y); q.z = to_fp8(v.z); q.w = to_fp8(v.w);
    *(uchar4*)(wq + i) = q;
}

// ---------------- fp8 block-scaled GEMM ----------------
// C[m,n] = sum_kb  sA[m,kb]*wS[nT,kb] * sum_{k in kb} Aq[m,k]*Bq[n,k]
// tile 128x128, BK=128 (one scale block per K-step), 4 waves of 64x64
__global__ __launch_bounds__(256) void fp8_blockgemm_kernel(
    const uint8_t* __restrict__ Aq, const uint8_t* __restrict__ Bq,
    const float* __restrict__ sa, const float* __restrict__ wscale,
    float* __restrict__ C, int mTiles)
{
    __shared__ uint8_t lA[128 * 128];
    __shared__ uint8_t lB[128 * 128];
    __shared__ float   lS[128];

    const int t      = threadIdx.x;
    const int nTiles = N_DIM / 128;               // 32
    int bid = blockIdx.x;
    int nwg = mTiles * nTiles;                    // multiple of 8
    int cpx = nwg >> 3;
    int swz = (bid & 7) * cpx + (bid >> 3);       // bijective XCD swizzle
    int mT = swz / nTiles, nT = swz % nTiles;
    const int m0 = mT * 128, n0 = nT * 128;

    const int lane = t & 63;
    const int wid  = t >> 6;
    const int wr   = (wid >> 1) * 64;             // wave row offset in tile
    const int wc   = (wid & 1) * 64;              // wave col offset in tile
    const int lr   = lane & 15;
    const int lk   = lane >> 4;                   // 0..3

    f32x4 acc[4][4] = {};
    const f32x4 vzero = {0.f, 0.f, 0.f, 0.f};

    const uint8_t* gA = Aq + (size_t)m0 * K_DIM;
    const uint8_t* gB = Bq + (size_t)n0 * K_DIM;

    for (int kb = 0; kb < KB_CNT; ++kb) {
        // ---- stage A,B tiles (pre-swizzled source -> linear LDS dest) ----
        #pragma unroll
        for (int i = 0; i < 4; ++i) {
            int p    = i * 4096 + t * 16;
            int row  = p >> 7;
            int col  = p & 127;
            int scol = col ^ ((row & 7) << 4);    // inverse of read swizzle
            size_t goff = (size_t)row * K_DIM + kb * 128 + scol;
            GLOAD_LDS16(gA + goff, &lA[p]);
            GLOAD_LDS16(gB + goff, &lB[p]);
        }
        if (t < 128) {
            float wsb = wscale[nT * KB_CNT + kb];
            lS[t] = sa[(size_t)(m0 + t) * KB_CNT + kb] * wsb;
        }
        __syncthreads();

        // ---- exact fp8 block-sum over this 128-K block ----
        f32x4 bs[4][4];
        {   // ks = 0 : init from zero C operand
            long af[4], bf[4];
            #pragma unroll
            for (int mi = 0; mi < 4; ++mi) {
                int row = wr + mi * 16 + lr;
                int kby = lk * 8;
                af[mi] = *(const long*)&lA[row * 128 + (kby ^ ((row & 7) << 4))];
            }
            #pragma unroll
            for (int ni = 0; ni < 4; ++ni) {
                int row = wc + ni * 16 + lr;
                int kby = lk * 8;
                bf[ni] = *(const long*)&lB[row * 128 + (kby ^ ((row & 7) << 4))];
            }
            #pragma unroll
            for (int mi = 0; mi < 4; ++mi)
                #pragma unroll
                for (int ni = 0; ni < 4; ++ni)
                    bs[mi][ni] = __builtin_amdgcn_mfma_f32_16x16x32_fp8_fp8(
                        af[mi], bf[ni], vzero, 0, 0, 0);
        }
        #pragma unroll
        for (int ks = 1; ks < 4; ++ks) {
            long af[4], bf[4];
            #pragma unroll
            for (int mi = 0; mi < 4; ++mi) {
                int row = wr + mi * 16 + lr;
                int kby = ks * 32 + lk * 8;
                af[mi] = *(const long*)&lA[row * 128 + (kby ^ ((row & 7) << 4))];
            }
            #pragma unroll
            for (int ni = 0; ni < 4; ++ni) {
                int row = wc + ni * 16 + lr;
                int kby = ks * 32 + lk * 8;
                bf[ni] = *(const long*)&lB[row * 128 + (kby ^ ((row & 7) << 4))];
            }
            #pragma unroll
            for (int mi = 0; mi < 4; ++mi)
                #pragma unroll
                for (int ni = 0; ni < 4; ++ni)
                    bs[mi][ni] = __builtin_amdgcn_mfma_f32_16x16x32_fp8_fp8(
                        af[mi], bf[ni], bs[mi][ni], 0, 0, 0);
        }

        // ---- apply combined scale (s_a[m,kb] * ws[nT,kb]) ----
        #pragma unroll
        for (int mi = 0; mi < 4; ++mi) {
            f32x4 s4 = *(const f32x4*)&lS[wr + mi * 16 + lk * 4];
            #pragma unroll
            for (int ni = 0; ni < 4; ++ni)
                acc[mi][ni] += bs[mi][ni] * s4;
        }
        __syncthreads();
    }

    // ---- epilogue: C/D layout col=lane&15, row=lk*4+j ----
    #pragma unroll
    for (int mi = 0; mi < 4; ++mi) {
        #pragma unroll
        for (int j = 0; j < 4; ++j) {
            int m = m0 + wr + mi * 16 + lk * 4 + j;
            float* crow = C + (size_t)m * N_DIM + n0 + wc;
            #pragma unroll
            for (int ni = 0; ni < 4; ++ni)
                crow[ni * 16 + lr] = acc[mi][ni][j];
        }
    }
}

extern "C" void kernel_launch(void* const* d_in, const int* in_sizes, int n_in,
                              void* d_out, int out_size, void* d_ws, size_t ws_size,
                              hipStream_t stream) {
    const float* x      = (const float*)d_in[0];
    const float* w      = (const float*)d_in[1];
    const float* wscale = (const float*)d_in[2];
    float* out = (float*)d_out;
    int M = in_sizes[0] / K_DIM;                  // 8192

    // workspace layout: xq [M*K] | wq [N*K] | sa [M*32] f32   (~49 MB)
    uint8_t* xq = (uint8_t*)d_ws;
    uint8_t* wq = xq + (size_t)M * K_DIM;
    float*   sa = (float*)(wq + (size_t)N_DIM * K_DIM);

    act_quant_kernel<<<M * KB_CNT / 4, 256, 0, stream>>>(x, xq, sa);
    w_quant_kernel<<<((size_t)N_DIM * K_DIM) / 1024, 256, 0, stream>>>(w, wq);

    int mTiles = M / 128;
    fp8_blockgemm_kernel<<<mTiles * (N_DIM / 128), 256, 0, stream>>>(
        xq, wq, sa, wscale, out, mTiles);
}